// Round 8
// baseline (505.824 us; speedup 1.0000x reference)
//
#include <hip/hip_runtime.h>
#include <hip/hip_bf16.h>
#include <stdint.h>

#define NC 2112   // H*DK*2 + DK = 16*64*2 + 64

typedef __attribute__((ext_vector_type(8))) short bf16x8;
typedef __attribute__((ext_vector_type(4))) float f32x4;

static __device__ __forceinline__ unsigned short f2bf(float f) {
  uint32_t u = __builtin_bit_cast(uint32_t, f);
  u += 0x7FFFu + ((u >> 16) & 1u);
  return (unsigned short)(u >> 16);
}
// native path: compiler emits v_cvt_pk_bf16_f32 (RNE, same bits as f2bf)
static __device__ __forceinline__ unsigned short f2bf_n(float f) {
  __hip_bfloat16 h = __float2bfloat16(f);
  return __builtin_bit_cast(unsigned short, h);
}
static __device__ __forceinline__ float bf2f(unsigned short u) {
  return __builtin_bit_cast(float, ((uint32_t)u) << 16);
}
static __device__ __forceinline__ void gload16(const unsigned short* g, unsigned short* l) {
  __builtin_amdgcn_global_load_lds((const __attribute__((address_space(1))) void*)g,
                                   (__attribute__((address_space(3))) void*)l, 16, 0, 0);
}

// ---------------- 1. q fp32 -> bf16 ----------------
__global__ void k_convert_q(const float* __restrict__ q, unsigned short* __restrict__ qbf) {
  int i = blockIdx.x * blockDim.x + threadIdx.x;   // one float4 each; 2,097,152 total
  float4 v = ((const float4*)q)[i];
  ushort4 o;
  o.x = f2bf(v.x); o.y = f2bf(v.y); o.z = f2bf(v.z); o.w = f2bf(v.w);
  ((ushort4*)qbf)[i] = o;
}

// ---------------- 2. build WcatT[2112][1024] bf16 (N-major, k contiguous) ----------------
__global__ void k_build_wcatT(const float* __restrict__ Wq, const float* __restrict__ Wk,
                              const float* __restrict__ Wv, unsigned short* __restrict__ wt) {
  int t = blockIdx.x * blockDim.x + threadIdx.x;   // c*128 + k/8 ; 270,336 total
  int c = t >> 7;
  int k0 = (t & 127) << 3;
  unsigned short o[8];
#pragma unroll
  for (int i = 0; i < 8; ++i) {
    int k = k0 + i;
    float v;
    if (c < 1024)      v = Wq[((size_t)(c >> 6) * 1024 + k) * 64 + (c & 63)];
    else if (c < 2048) v = Wk[((size_t)((c - 1024) >> 6) * 1024 + k) * 64 + (c & 63)];
    else               v = Wv[(size_t)k * 64 + (c - 2048)];
    o[i] = f2bf(v);
  }
  *(ushort4*)&wt[(size_t)c * 1024 + k0]     = *(ushort4*)&o[0];
  *(ushort4*)&wt[(size_t)c * 1024 + k0 + 4] = *(ushort4*)&o[4];
}

// ---------------- 3. GEMM (m97 pattern) + fused V-transpose epilogue ----------------
__global__ __launch_bounds__(256) void k_gemm(const unsigned short* __restrict__ A,
                                              const unsigned short* __restrict__ Bt,
                                              unsigned short* __restrict__ C,
                                              unsigned short* __restrict__ vst) {
  __shared__ unsigned short As[128 * 32];   // linear: required by global_load_lds
  __shared__ unsigned short Bs[128 * 32];
  const int L = blockIdx.x;                 // XCD swizzle: 1088 = 8 * 136
  const int wi = (L & 7) * 136 + (L >> 3);
  const int tn = wi % 17, tm = wi / 17;
  const int rowBase = tm * 128, colBase = tn * 128;
  const int t = threadIdx.x;
  const int wave = t >> 6, lane = t & 63;
  const int wm = wave >> 1, wn = wave & 1;
  const int l15 = lane & 15, l4 = lane >> 4;
  f32x4 acc[4][4] = {};
  for (int kt = 0; kt < 1024; kt += 32) {
#pragma unroll
    for (int i = 0; i < 2; ++i) {
      int e = (t + i * 256) * 8;          // elem index in 128x32 tile
      int r = e >> 5, c = e & 31;
      gload16(&A[(size_t)(rowBase + r) * 1024 + kt + c], &As[e]);
      int rb = colBase + r; rb = rb < NC ? rb : (NC - 1);   // clamp (dup row, never stored)
      gload16(&Bt[(size_t)rb * 1024 + kt + c], &Bs[e]);
    }
    __syncthreads();
    bf16x8 af[4], bfr[4];
#pragma unroll
    for (int m = 0; m < 4; ++m) af[m] = *(const bf16x8*)&As[(wm * 64 + m * 16 + l15) * 32 + l4 * 8];
#pragma unroll
    for (int n = 0; n < 4; ++n) bfr[n] = *(const bf16x8*)&Bs[(wn * 64 + n * 16 + l15) * 32 + l4 * 8];
#pragma unroll
    for (int m = 0; m < 4; ++m)
#pragma unroll
      for (int n = 0; n < 4; ++n)
        acc[m][n] = __builtin_amdgcn_mfma_f32_16x16x32_bf16(af[m], bfr[n], acc[m][n], 0, 0, 0);
    __syncthreads();
  }
#pragma unroll
  for (int m = 0; m < 4; ++m)
#pragma unroll
    for (int n = 0; n < 4; ++n) {
      int col = colBase + wn * 64 + n * 16 + l15;
      int row0 = rowBase + wm * 64 + m * 16 + l4 * 4;
      if (col < 2048) {
#pragma unroll
        for (int i = 0; i < 4; ++i)
          C[(size_t)(row0 + i) * NC + col] = f2bf_n(acc[m][n][i]);
      } else if (col < NC) {
        // V columns: write transposed into vst[b][d][j]
        int d = col - 2048;
#pragma unroll
        for (int i = 0; i < 4; ++i) {
          int rg = row0 + i;
          vst[((size_t)(rg >> 10) * 64 + d) * 1024 + (rg & 1023)] = f2bf_n(acc[m][n][i]);
        }
      }
    }
}

// ---------------- 4a. row-sum pass: inv[row] = 1/sum_j exp(s/8) ----------------
// Wave owns a 16-row strip x all 1024 keys. No LDS, no barriers, tiny output.
__global__ __launch_bounds__(256, 8) void k_sums(const unsigned short* __restrict__ G,
                                                 float* __restrict__ invs) {
  const int L = blockIdx.x;                  // 2048 = 8 * 256 (XCD-chunked)
  const int wi = (L & 7) * 256 + (L >> 3);
  const int qt = wi & 15, b = (wi >> 4) & 7, h = wi >> 7;
  const int t = threadIdx.x, wave = t >> 6, lane = t & 63;
  const int l15 = lane & 15, l4 = lane >> 4;
  const int qrow0 = qt * 64 + wave * 16;
  const float scale = 0.125f;

  const unsigned short* Gb = G + (size_t)b * 1024 * NC;
  const unsigned short* Kb = Gb + 1024 + h * 64 + l4 * 8;
  const unsigned short* Qp = Gb + (size_t)(qrow0 + l15) * NC + h * 64 + l4 * 8;
  bf16x8 qf0 = *(const bf16x8*)Qp;
  bf16x8 qf1 = *(const bf16x8*)(Qp + 32);

  float psum[4] = {};
#pragma unroll 2
  for (int seg = 0; seg < 16; ++seg) {
    bf16x8 kf[4][2];
#pragma unroll
    for (int kt = 0; kt < 4; ++kt) {
      const unsigned short* kp = Kb + (size_t)(seg * 64 + kt * 16 + l15) * NC;
      kf[kt][0] = *(const bf16x8*)kp;
      kf[kt][1] = *(const bf16x8*)(kp + 32);
    }
#pragma unroll
    for (int kt = 0; kt < 4; ++kt) {
      f32x4 s = {};
      s = __builtin_amdgcn_mfma_f32_16x16x32_bf16(qf0, kf[kt][0], s, 0, 0, 0);
      s = __builtin_amdgcn_mfma_f32_16x16x32_bf16(qf1, kf[kt][1], s, 0, 0, 0);
#pragma unroll
      for (int i = 0; i < 4; ++i) psum[i] += __expf(s[i] * scale);
    }
  }
#pragma unroll
  for (int off = 1; off < 16; off <<= 1)
#pragma unroll
    for (int i = 0; i < 4; ++i) psum[i] += __shfl_xor(psum[i], off);
  if (l15 == 0) {
    size_t base = (size_t)(h * 8 + b) * 1024 + qrow0 + l4 * 4;
#pragma unroll
    for (int i = 0; i < 4; ++i) invs[base + i] = 1.0f / psum[i];
  }
}

// ---------------- 4b. attention main: barrier-free streaming writer + fused PV ----------------
// Wave owns 16 rows x 1024 keys; inv known at entry. Per 64-key chunk:
// QK^T -> p = exp(s)*inv (fp32, final) -> private LDS chunk -> 4 fat float4 stores + PV.
// Stores are PLAIN (through L2): NT bypassed L2 write-combining and capped at ~2 TB/s.
__global__ __launch_bounds__(256, 5) void k_attn(const unsigned short* __restrict__ G,
                                                 const unsigned short* __restrict__ vst,
                                                 const float* __restrict__ invs,
                                                 float* __restrict__ attn,
                                                 float* __restrict__ head) {
  __shared__ float SPw[4][16][68];           // per-wave normalized-P chunk (17.4 KB)
  const int L = blockIdx.x;                  // 2048 = 8 * 256 (XCD-chunked)
  const int wi = (L & 7) * 256 + (L >> 3);
  const int qt = wi & 15, b = (wi >> 4) & 7, h = wi >> 7;
  const int t = threadIdx.x, wave = t >> 6, lane = t & 63;
  const int l15 = lane & 15, l4 = lane >> 4;
  const int qrow0 = qt * 64 + wave * 16;
  const float scale = 0.125f;

  const unsigned short* Gb = G + (size_t)b * 1024 * NC;
  const unsigned short* Kb = Gb + 1024 + h * 64 + l4 * 8;
  const unsigned short* Qp = Gb + (size_t)(qrow0 + l15) * NC + h * 64 + l4 * 8;
  bf16x8 qf0 = *(const bf16x8*)Qp;
  bf16x8 qf1 = *(const bf16x8*)(Qp + 32);

  // per-lane inverse sums for rows l4*4+i (precomputed by k_sums)
  float inv[4];
  {
    size_t base = (size_t)(h * 8 + b) * 1024 + qrow0 + l4 * 4;
#pragma unroll
    for (int i = 0; i < 4; ++i) inv[i] = invs[base + i];
  }

  size_t abase = ((size_t)(h * 8 + b) * 1024 + qrow0) * 1024;
  const unsigned short* Vb = vst + (size_t)b * 65536 + (size_t)l15 * 1024 + l4 * 8;
  float (*SP)[68] = SPw[wave];
  // write-out / PV addressing
  const int srow = lane >> 4;          // store: rows j*4+srow
  const int skey = (lane & 15) * 4;    // store: 4 consecutive keys
  f32x4 oacc[4] = {};

  for (int seg = 0; seg < 16; ++seg) {
    bf16x8 kf[4][2];
#pragma unroll
    for (int kt = 0; kt < 4; ++kt) {
      const unsigned short* kp = Kb + (size_t)(seg * 64 + kt * 16 + l15) * NC;
      kf[kt][0] = *(const bf16x8*)kp;
      kf[kt][1] = *(const bf16x8*)(kp + 32);
    }
#pragma unroll
    for (int kt = 0; kt < 4; ++kt) {
      f32x4 s = {};
      s = __builtin_amdgcn_mfma_f32_16x16x32_bf16(qf0, kf[kt][0], s, 0, 0, 0);
      s = __builtin_amdgcn_mfma_f32_16x16x32_bf16(qf1, kf[kt][1], s, 0, 0, 0);
#pragma unroll
      for (int i = 0; i < 4; ++i)
        SP[l4 * 4 + i][kt * 16 + l15] = __expf(s[i] * scale) * inv[i];
    }
    // ---- stream normalized fp32 attn out: 4 fat stores (1 KB each), through L2 ----
#pragma unroll
    for (int j = 0; j < 4; ++j) {
      f32x4 p = *(const f32x4*)&SP[j * 4 + srow][skey];
      *(f32x4*)&attn[abase + (size_t)(j * 4 + srow) * 1024 + seg * 64 + skey] = p;
    }
    // ---- fused PV on this chunk (A-frags from LDS, f32 -> bf16) ----
    bf16x8 pa0, pa1;
    {
      f32x4 r0 = *(const f32x4*)&SP[l15][l4 * 8];
      f32x4 r1 = *(const f32x4*)&SP[l15][l4 * 8 + 4];
      f32x4 r2 = *(const f32x4*)&SP[l15][32 + l4 * 8];
      f32x4 r3 = *(const f32x4*)&SP[l15][32 + l4 * 8 + 4];
      unsigned short u0[8] = {f2bf_n(r0[0]), f2bf_n(r0[1]), f2bf_n(r0[2]), f2bf_n(r0[3]),
                              f2bf_n(r1[0]), f2bf_n(r1[1]), f2bf_n(r1[2]), f2bf_n(r1[3])};
      unsigned short u1[8] = {f2bf_n(r2[0]), f2bf_n(r2[1]), f2bf_n(r2[2]), f2bf_n(r2[3]),
                              f2bf_n(r3[0]), f2bf_n(r3[1]), f2bf_n(r3[2]), f2bf_n(r3[3])};
      pa0 = *(const bf16x8*)u0;
      pa1 = *(const bf16x8*)u1;
    }
#pragma unroll
    for (int n = 0; n < 4; ++n) {
      const unsigned short* vp = Vb + (size_t)n * 16384 + seg * 64;
      bf16x8 v0 = *(const bf16x8*)vp;
      bf16x8 v1 = *(const bf16x8*)(vp + 32);
      oacc[n] = __builtin_amdgcn_mfma_f32_16x16x32_bf16(pa0, v0, oacc[n], 0, 0, 0);
      oacc[n] = __builtin_amdgcn_mfma_f32_16x16x32_bf16(pa1, v1, oacc[n], 0, 0, 0);
    }
  }
  // head: already normalized (P was pre-scaled by inv)
  float* hb = head + ((size_t)(h * 8 + b) * 1024 + qrow0) * 64;
#pragma unroll
  for (int n = 0; n < 4; ++n)
#pragma unroll
    for (int i = 0; i < 4; ++i)
      hb[(size_t)(l4 * 4 + i) * 64 + n * 16 + l15] = oacc[n][i];
}

// ---------------- 5. fused head-mean + out = pooled @ Wo ----------------
__global__ __launch_bounds__(256) void k_final(const float* __restrict__ head,
                                               const float* __restrict__ Wo,
                                               float* __restrict__ out) {
  __shared__ float Ps[16][68];
  __shared__ float Ws[64][132];
  const int rt = blockIdx.x;            // 512 blocks, 16 rows each
  const int r0 = rt * 16;
  const int t = threadIdx.x;
  {
    int r = t >> 4, k4 = (t & 15) * 4;  // 256 threads = 16 rows x 16 float4
    float4 acc = {0.f, 0.f, 0.f, 0.f};
#pragma unroll
    for (int hh = 0; hh < 16; ++hh) {
      float4 v = *(const float4*)&head[((size_t)hh * 8192 + r0 + r) * 64 + k4];
      acc.x += v.x; acc.y += v.y; acc.z += v.z; acc.w += v.w;
    }
    const float s = 1.0f / 16.0f;
    Ps[r][k4] = acc.x * s; Ps[r][k4 + 1] = acc.y * s;
    Ps[r][k4 + 2] = acc.z * s; Ps[r][k4 + 3] = acc.w * s;
  }
  const int ty = t >> 4, tx = t & 15;
  for (int dt = 0; dt < 8; ++dt) {
    int d0 = dt * 128;
#pragma unroll
    for (int j = 0; j < 8; ++j) {
      int e = t + j * 256;
      int k = e >> 5, c4 = (e & 31) * 4;
      *(float4*)&Ws[k][c4] = *(const float4*)&Wo[(size_t)k * 1024 + d0 + c4];
    }
    __syncthreads();
    float acc[8] = {};
    for (int k = 0; k < 64; ++k) {
      float a0 = Ps[ty][k];
      float4 b0 = *(const float4*)&Ws[k][tx * 8];
      float4 b1 = *(const float4*)&Ws[k][tx * 8 + 4];
      acc[0] += a0 * b0.x; acc[1] += a0 * b0.y; acc[2] += a0 * b0.z; acc[3] += a0 * b0.w;
      acc[4] += a0 * b1.x; acc[5] += a0 * b1.y; acc[6] += a0 * b1.z; acc[7] += a0 * b1.w;
    }
    float4 v0 = {acc[0], acc[1], acc[2], acc[3]};
    float4 v1 = {acc[4], acc[5], acc[6], acc[7]};
    size_t o = (size_t)(r0 + ty) * 1024 + d0 + tx * 8;
    *(float4*)&out[o]     = v0;
    *(float4*)&out[o + 4] = v1;
    __syncthreads();
  }
}

extern "C" void kernel_launch(void* const* d_in, const int* in_sizes, int n_in,
                              void* d_out, int out_size, void* d_ws, size_t ws_size,
                              hipStream_t stream) {
  const float* q  = (const float*)d_in[0];
  // d_in[1] (k), d_in[2] (v) are unused by the reference
  const float* Wq = (const float*)d_in[3];
  const float* Wk = (const float*)d_in[4];
  const float* Wv = (const float*)d_in[5];
  const float* Wo = (const float*)d_in[6];

  char* ws = (char*)d_ws;
  unsigned short* qbf   = (unsigned short*)(ws + 0);          // 16,777,216 B
  unsigned short* wcatT = (unsigned short*)(ws + 16777216);   //  4,325,376 B
  unsigned short* G     = (unsigned short*)(ws + 21102592);   // 34,603,008 B
  unsigned short* vst   = (unsigned short*)(ws + 55705600);   //  1,048,576 B
  float*          head  = (float*)(ws + 56754176);            // 33,554,432 B
  float*          invs  = (float*)(ws + 90308608);            //    524,288 B

  float* out  = (float*)d_out;
  float* attn = out + (size_t)8 * 1024 * 1024;

  hipLaunchKernelGGL(k_convert_q,   dim3(8192), dim3(256), 0, stream, q, qbf);
  hipLaunchKernelGGL(k_build_wcatT, dim3(1056), dim3(256), 0, stream, Wq, Wk, Wv, wcatT);
  hipLaunchKernelGGL(k_gemm,        dim3(1088), dim3(256), 0, stream, qbf, wcatT, G, vst);
  hipLaunchKernelGGL(k_sums,        dim3(2048), dim3(256), 0, stream, G, invs);
  hipLaunchKernelGGL(k_attn,        dim3(2048), dim3(256), 0, stream, G, vst, invs, attn, head);
  hipLaunchKernelGGL(k_final,       dim3(512),  dim3(256), 0, stream, head, Wo, out);
}

// Round 9
// 378.974 us; speedup vs baseline: 1.3347x; 1.3347x over previous
//
#include <hip/hip_runtime.h>
#include <hip/hip_bf16.h>
#include <stdint.h>

#define NC 2112   // H*DK*2 + DK = 16*64*2 + 64

typedef __attribute__((ext_vector_type(8))) short bf16x8;
typedef __attribute__((ext_vector_type(4))) float f32x4;

static __device__ __forceinline__ unsigned short f2bf(float f) {
  uint32_t u = __builtin_bit_cast(uint32_t, f);
  u += 0x7FFFu + ((u >> 16) & 1u);
  return (unsigned short)(u >> 16);
}
// native path: compiler emits v_cvt_pk_bf16_f32 (RNE, same bits as f2bf)
static __device__ __forceinline__ unsigned short f2bf_n(float f) {
  __hip_bfloat16 h = __float2bfloat16(f);
  return __builtin_bit_cast(unsigned short, h);
}
static __device__ __forceinline__ float bf2f(unsigned short u) {
  return __builtin_bit_cast(float, ((uint32_t)u) << 16);
}
static __device__ __forceinline__ void gload16(const unsigned short* g, unsigned short* l) {
  __builtin_amdgcn_global_load_lds((const __attribute__((address_space(1))) void*)g,
                                   (__attribute__((address_space(3))) void*)l, 16, 0, 0);
}

// ---------------- 1. q fp32 -> bf16 ----------------
__global__ void k_convert_q(const float* __restrict__ q, unsigned short* __restrict__ qbf) {
  int i = blockIdx.x * blockDim.x + threadIdx.x;   // one float4 each; 2,097,152 total
  float4 v = ((const float4*)q)[i];
  ushort4 o;
  o.x = f2bf(v.x); o.y = f2bf(v.y); o.z = f2bf(v.z); o.w = f2bf(v.w);
  ((ushort4*)qbf)[i] = o;
}

// ---------------- 2. build WcatT[2112][1024] bf16 (N-major, k contiguous) ----------------
__global__ void k_build_wcatT(const float* __restrict__ Wq, const float* __restrict__ Wk,
                              const float* __restrict__ Wv, unsigned short* __restrict__ wt) {
  int t = blockIdx.x * blockDim.x + threadIdx.x;   // c*128 + k/8 ; 270,336 total
  int c = t >> 7;
  int k0 = (t & 127) << 3;
  unsigned short o[8];
#pragma unroll
  for (int i = 0; i < 8; ++i) {
    int k = k0 + i;
    float v;
    if (c < 1024)      v = Wq[((size_t)(c >> 6) * 1024 + k) * 64 + (c & 63)];
    else if (c < 2048) v = Wk[((size_t)((c - 1024) >> 6) * 1024 + k) * 64 + (c & 63)];
    else               v = Wv[(size_t)k * 64 + (c - 2048)];
    o[i] = f2bf(v);
  }
  *(ushort4*)&wt[(size_t)c * 1024 + k0]     = *(ushort4*)&o[0];
  *(ushort4*)&wt[(size_t)c * 1024 + k0 + 4] = *(ushort4*)&o[4];
}

// ---------------- 3. GEMM (m97 pattern) + fused V-transpose epilogue ----------------
__global__ __launch_bounds__(256) void k_gemm(const unsigned short* __restrict__ A,
                                              const unsigned short* __restrict__ Bt,
                                              unsigned short* __restrict__ C,
                                              unsigned short* __restrict__ vst) {
  __shared__ unsigned short As[128 * 32];   // linear: required by global_load_lds
  __shared__ unsigned short Bs[128 * 32];
  const int L = blockIdx.x;                 // XCD swizzle: 1088 = 8 * 136
  const int wi = (L & 7) * 136 + (L >> 3);
  const int tn = wi % 17, tm = wi / 17;
  const int rowBase = tm * 128, colBase = tn * 128;
  const int t = threadIdx.x;
  const int wave = t >> 6, lane = t & 63;
  const int wm = wave >> 1, wn = wave & 1;
  const int l15 = lane & 15, l4 = lane >> 4;
  f32x4 acc[4][4] = {};
  for (int kt = 0; kt < 1024; kt += 32) {
#pragma unroll
    for (int i = 0; i < 2; ++i) {
      int e = (t + i * 256) * 8;          // elem index in 128x32 tile
      int r = e >> 5, c = e & 31;
      gload16(&A[(size_t)(rowBase + r) * 1024 + kt + c], &As[e]);
      int rb = colBase + r; rb = rb < NC ? rb : (NC - 1);   // clamp (dup row, never stored)
      gload16(&Bt[(size_t)rb * 1024 + kt + c], &Bs[e]);
    }
    __syncthreads();
    bf16x8 af[4], bfr[4];
#pragma unroll
    for (int m = 0; m < 4; ++m) af[m] = *(const bf16x8*)&As[(wm * 64 + m * 16 + l15) * 32 + l4 * 8];
#pragma unroll
    for (int n = 0; n < 4; ++n) bfr[n] = *(const bf16x8*)&Bs[(wn * 64 + n * 16 + l15) * 32 + l4 * 8];
#pragma unroll
    for (int m = 0; m < 4; ++m)
#pragma unroll
      for (int n = 0; n < 4; ++n)
        acc[m][n] = __builtin_amdgcn_mfma_f32_16x16x32_bf16(af[m], bfr[n], acc[m][n], 0, 0, 0);
    __syncthreads();
  }
#pragma unroll
  for (int m = 0; m < 4; ++m)
#pragma unroll
    for (int n = 0; n < 4; ++n) {
      int col = colBase + wn * 64 + n * 16 + l15;
      int row0 = rowBase + wm * 64 + m * 16 + l4 * 4;
      if (col < 2048) {
#pragma unroll
        for (int i = 0; i < 4; ++i)
          C[(size_t)(row0 + i) * NC + col] = f2bf_n(acc[m][n][i]);
      } else if (col < NC) {
        // V columns: write transposed into vst[b][d][j]
        int d = col - 2048;
#pragma unroll
        for (int i = 0; i < 4; ++i) {
          int rg = row0 + i;
          vst[((size_t)(rg >> 10) * 64 + d) * 1024 + (rg & 1023)] = f2bf_n(acc[m][n][i]);
        }
      }
    }
}

// ---------------- 4. attention (r4 champion + swapped-operand QK^T, PV-first epilogue) ----------------
// Block = 8 waves x 512 threads, QBLK=32 rows, single barrier.
// Phase 1: wave owns keys [wave*128,+128): s = mfma(K,Q) -> lane holds 4 consecutive
//          keys of one q-row -> exp -> cvt_pk -> ds_write_b64; row sums via 2 shfl_xor.
// Phase 2: PV first (MFMA), then attn NT-stores last (drain past wave end).
__global__ __launch_bounds__(512, 4) void k_attn(const unsigned short* __restrict__ G,
                                                 const unsigned short* __restrict__ vst,
                                                 float* __restrict__ attn,
                                                 float* __restrict__ head) {
  __shared__ unsigned short SP[32][1032];  // unnormalized exp(scores), bf16
  __shared__ float rs[32][8];              // per-row partial sums, per wave
  const int L = blockIdx.x;                // XCD swizzle: 4096 = 8 * 512
  const int wi = (L & 7) * 512 + (L >> 3);
  const int qt = wi & 31, b = (wi >> 5) & 7, h = wi >> 8;
  const int t = threadIdx.x, wave = t >> 6, lane = t & 63;
  const int l15 = lane & 15, l4 = lane >> 4;
  const float scale = 0.125f;  // 1/sqrt(64)

  const unsigned short* Gb = G + (size_t)b * 1024 * NC;

  // Q fragments (B-operand now): qf[m][ks] covers q-rows qt*32+m*16+l15
  bf16x8 qf[2][2];
#pragma unroll
  for (int m = 0; m < 2; ++m)
#pragma unroll
    for (int ks = 0; ks < 2; ++ks)
      qf[m][ks] = *(const bf16x8*)&Gb[(size_t)(qt * 32 + m * 16 + l15) * NC + h * 64 + ks * 32 + l4 * 8];

  // ---- phase 1: QK^T (swapped operands), exp, LDS stage, partial row sums ----
  float psum[2] = {};   // row m*16+l15, this wave's 128 keys
#pragma unroll
  for (int half = 0; half < 2; ++half) {
    bf16x8 kf[4][2];
#pragma unroll
    for (int kt = 0; kt < 4; ++kt) {
      int k0 = wave * 128 + half * 64 + kt * 16;
#pragma unroll
      for (int ks = 0; ks < 2; ++ks)
        kf[kt][ks] = *(const bf16x8*)&Gb[(size_t)(k0 + l15) * NC + 1024 + h * 64 + ks * 32 + l4 * 8];
    }
#pragma unroll
    for (int kt = 0; kt < 4; ++kt) {
      int k0 = wave * 128 + half * 64 + kt * 16;
#pragma unroll
      for (int m = 0; m < 2; ++m) {
        f32x4 s = {};
        s = __builtin_amdgcn_mfma_f32_16x16x32_bf16(kf[kt][0], qf[m][0], s, 0, 0, 0);
        s = __builtin_amdgcn_mfma_f32_16x16x32_bf16(kf[kt][1], qf[m][1], s, 0, 0, 0);
        // lane: q-row = m*16+l15 ; keys = k0 + l4*4 + i
        float e0 = __expf(s[0] * scale), e1 = __expf(s[1] * scale);
        float e2 = __expf(s[2] * scale), e3 = __expf(s[3] * scale);
        psum[m] += (e0 + e1) + (e2 + e3);
        uint32_t lo = (uint32_t)f2bf_n(e0) | ((uint32_t)f2bf_n(e1) << 16);
        uint32_t hi = (uint32_t)f2bf_n(e2) | ((uint32_t)f2bf_n(e3) << 16);
        uint2 u = {lo, hi};
        *(uint2*)&SP[m * 16 + l15][k0 + l4 * 4] = u;
      }
    }
  }
  // reduce over l4 (lane bits 4-5): all 4 lanes of a row share psum
#pragma unroll
  for (int m = 0; m < 2; ++m) {
    psum[m] += __shfl_xor(psum[m], 16);
    psum[m] += __shfl_xor(psum[m], 32);
  }
  if (l4 == 0) {
    rs[l15][wave]      = psum[0];
    rs[16 + l15][wave] = psum[1];
  }
  __syncthreads();

  // ---- per-row inverse sums ----
  const int wm = wave >> 2, wn = wave & 3;
  float winv[4], pinv[4];
#pragma unroll
  for (int rr = 0; rr < 4; ++rr) {
    int row = wave * 4 + rr;
    float4 a = *(const float4*)&rs[row][0];
    float4 c = *(const float4*)&rs[row][4];
    winv[rr] = 1.0f / (a.x + a.y + a.z + a.w + c.x + c.y + c.z + c.w);
  }
#pragma unroll
  for (int i = 0; i < 4; ++i) {
    int row = wm * 16 + l4 * 4 + i;
    float4 a = *(const float4*)&rs[row][0];
    float4 c = *(const float4*)&rs[row][4];
    pinv[i] = 1.0f / (a.x + a.y + a.z + a.w + c.x + c.y + c.z + c.w);
  }

  // ---- phase 2a: PV (wave owns 16x16 tile (wm,wn)); unnormalized P, scale at end ----
  const unsigned short* vb = vst + ((size_t)b * 64 + wn * 16 + l15) * 1024;
  const unsigned short* pr = &SP[wm * 16 + l15][0];
  f32x4 o0 = {}, o1 = {};
#pragma unroll 8
  for (int jt = 0; jt < 32; jt += 2) {
    bf16x8 pa0 = *(const bf16x8*)&pr[jt * 32 + l4 * 8];
    bf16x8 bv0 = *(const bf16x8*)&vb[jt * 32 + l4 * 8];
    o0 = __builtin_amdgcn_mfma_f32_16x16x32_bf16(pa0, bv0, o0, 0, 0, 0);
    bf16x8 pa1 = *(const bf16x8*)&pr[(jt + 1) * 32 + l4 * 8];
    bf16x8 bv1 = *(const bf16x8*)&vb[(jt + 1) * 32 + l4 * 8];
    o1 = __builtin_amdgcn_mfma_f32_16x16x32_bf16(pa1, bv1, o1, 0, 0, 0);
  }
  float* hb = head + (((size_t)(h * 8 + b) * 1024) + qt * 32 + wm * 16) * 64 + wn * 16;
#pragma unroll
  for (int i = 0; i < 4; ++i)
    hb[(size_t)(l4 * 4 + i) * 64 + l15] = (o0[i] + o1[i]) * pinv[i];

  // ---- phase 2b: attn write LAST (rows wave*4..+3); NT stores drain past wave end ----
  size_t attn_base = ((size_t)(h * 8 + b) * 1024 + (size_t)qt * 32) * 1024;
#pragma unroll
  for (int rr = 0; rr < 4; ++rr) {
    int row = wave * 4 + rr;
    float inv = winv[rr];
#pragma unroll
    for (int c = 0; c < 2; ++c) {
      uint4 u = *(const uint4*)&SP[row][c * 512 + lane * 8];
      f32x4 p0 = {bf2f((unsigned short)(u.x & 0xFFFF)) * inv,
                  bf2f((unsigned short)(u.x >> 16)) * inv,
                  bf2f((unsigned short)(u.y & 0xFFFF)) * inv,
                  bf2f((unsigned short)(u.y >> 16)) * inv};
      f32x4 p1 = {bf2f((unsigned short)(u.z & 0xFFFF)) * inv,
                  bf2f((unsigned short)(u.z >> 16)) * inv,
                  bf2f((unsigned short)(u.w & 0xFFFF)) * inv,
                  bf2f((unsigned short)(u.w >> 16)) * inv};
      float* ab = &attn[attn_base + (size_t)row * 1024 + c * 512 + lane * 8];
      __builtin_nontemporal_store(p0, (f32x4*)ab);
      __builtin_nontemporal_store(p1, (f32x4*)(ab + 4));
    }
  }
}

// ---------------- 5. fused head-mean + out = pooled @ Wo ----------------
__global__ __launch_bounds__(256) void k_final(const float* __restrict__ head,
                                               const float* __restrict__ Wo,
                                               float* __restrict__ out) {
  __shared__ float Ps[16][68];
  __shared__ float Ws[64][132];
  const int rt = blockIdx.x;            // 512 blocks, 16 rows each
  const int r0 = rt * 16;
  const int t = threadIdx.x;
  {
    int r = t >> 4, k4 = (t & 15) * 4;  // 256 threads = 16 rows x 16 float4
    float4 acc = {0.f, 0.f, 0.f, 0.f};
#pragma unroll
    for (int hh = 0; hh < 16; ++hh) {
      float4 v = *(const float4*)&head[((size_t)hh * 8192 + r0 + r) * 64 + k4];
      acc.x += v.x; acc.y += v.y; acc.z += v.z; acc.w += v.w;
    }
    const float s = 1.0f / 16.0f;
    Ps[r][k4] = acc.x * s; Ps[r][k4 + 1] = acc.y * s;
    Ps[r][k4 + 2] = acc.z * s; Ps[r][k4 + 3] = acc.w * s;
  }
  const int ty = t >> 4, tx = t & 15;
  for (int dt = 0; dt < 8; ++dt) {
    int d0 = dt * 128;
#pragma unroll
    for (int j = 0; j < 8; ++j) {
      int e = t + j * 256;
      int k = e >> 5, c4 = (e & 31) * 4;
      *(float4*)&Ws[k][c4] = *(const float4*)&Wo[(size_t)k * 1024 + d0 + c4];
    }
    __syncthreads();
    float acc[8] = {};
    for (int k = 0; k < 64; ++k) {
      float a0 = Ps[ty][k];
      float4 b0 = *(const float4*)&Ws[k][tx * 8];
      float4 b1 = *(const float4*)&Ws[k][tx * 8 + 4];
      acc[0] += a0 * b0.x; acc[1] += a0 * b0.y; acc[2] += a0 * b0.z; acc[3] += a0 * b0.w;
      acc[4] += a0 * b1.x; acc[5] += a0 * b1.y; acc[6] += a0 * b1.z; acc[7] += a0 * b1.w;
    }
    float4 v0 = {acc[0], acc[1], acc[2], acc[3]};
    float4 v1 = {acc[4], acc[5], acc[6], acc[7]};
    size_t o = (size_t)(r0 + ty) * 1024 + d0 + tx * 8;
    *(float4*)&out[o]     = v0;
    *(float4*)&out[o + 4] = v1;
    __syncthreads();
  }
}

extern "C" void kernel_launch(void* const* d_in, const int* in_sizes, int n_in,
                              void* d_out, int out_size, void* d_ws, size_t ws_size,
                              hipStream_t stream) {
  const float* q  = (const float*)d_in[0];
  // d_in[1] (k), d_in[2] (v) are unused by the reference
  const float* Wq = (const float*)d_in[3];
  const float* Wk = (const float*)d_in[4];
  const float* Wv = (const float*)d_in[5];
  const float* Wo = (const float*)d_in[6];

  char* ws = (char*)d_ws;
  unsigned short* qbf   = (unsigned short*)(ws + 0);          // 16,777,216 B
  unsigned short* wcatT = (unsigned short*)(ws + 16777216);   //  4,325,376 B
  unsigned short* G     = (unsigned short*)(ws + 21102592);   // 34,603,008 B
  unsigned short* vst   = (unsigned short*)(ws + 55705600);   //  1,048,576 B
  float*          head  = (float*)(ws + 56754176);            // 33,554,432 B

  float* out  = (float*)d_out;
  float* attn = out + (size_t)8 * 1024 * 1024;

  hipLaunchKernelGGL(k_convert_q,   dim3(8192), dim3(256), 0, stream, q, qbf);
  hipLaunchKernelGGL(k_build_wcatT, dim3(1056), dim3(256), 0, stream, Wq, Wk, Wv, wcatT);
  hipLaunchKernelGGL(k_gemm,        dim3(1088), dim3(256), 0, stream, qbf, wcatT, G, vst);
  hipLaunchKernelGGL(k_attn,        dim3(4096), dim3(512), 0, stream, G, vst, attn, head);
  hipLaunchKernelGGL(k_final,       dim3(512),  dim3(256), 0, stream, head, Wo, out);
}

// Round 10
// 355.715 us; speedup vs baseline: 1.4220x; 1.0654x over previous
//
#include <hip/hip_runtime.h>
#include <hip/hip_bf16.h>
#include <stdint.h>

#define NC 2112   // H*DK*2 + DK = 16*64*2 + 64

typedef __attribute__((ext_vector_type(8))) short bf16x8;
typedef __attribute__((ext_vector_type(4))) float f32x4;

static __device__ __forceinline__ unsigned short f2bf(float f) {
  uint32_t u = __builtin_bit_cast(uint32_t, f);
  u += 0x7FFFu + ((u >> 16) & 1u);
  return (unsigned short)(u >> 16);
}
// native path: compiler emits v_cvt_pk_bf16_f32 (RNE, same bits as f2bf)
static __device__ __forceinline__ unsigned short f2bf_n(float f) {
  __hip_bfloat16 h = __float2bfloat16(f);
  return __builtin_bit_cast(unsigned short, h);
}
static __device__ __forceinline__ float bf2f(unsigned short u) {
  return __builtin_bit_cast(float, ((uint32_t)u) << 16);
}
static __device__ __forceinline__ void gload16(const unsigned short* g, unsigned short* l) {
  __builtin_amdgcn_global_load_lds((const __attribute__((address_space(1))) void*)g,
                                   (__attribute__((address_space(3))) void*)l, 16, 0, 0);
}

// ---------------- 1. q fp32 -> bf16 ----------------
__global__ void k_convert_q(const float* __restrict__ q, unsigned short* __restrict__ qbf) {
  int i = blockIdx.x * blockDim.x + threadIdx.x;   // one float4 each; 2,097,152 total
  float4 v = ((const float4*)q)[i];
  ushort4 o;
  o.x = f2bf(v.x); o.y = f2bf(v.y); o.z = f2bf(v.z); o.w = f2bf(v.w);
  ((ushort4*)qbf)[i] = o;
}

// ---------------- 2. build WcatT[2112][1024] bf16 (N-major, k contiguous) ----------------
__global__ void k_build_wcatT(const float* __restrict__ Wq, const float* __restrict__ Wk,
                              const float* __restrict__ Wv, unsigned short* __restrict__ wt) {
  int t = blockIdx.x * blockDim.x + threadIdx.x;   // c*128 + k/8 ; 270,336 total
  int c = t >> 7;
  int k0 = (t & 127) << 3;
  unsigned short o[8];
#pragma unroll
  for (int i = 0; i < 8; ++i) {
    int k = k0 + i;
    float v;
    if (c < 1024)      v = Wq[((size_t)(c >> 6) * 1024 + k) * 64 + (c & 63)];
    else if (c < 2048) v = Wk[((size_t)((c - 1024) >> 6) * 1024 + k) * 64 + (c & 63)];
    else               v = Wv[(size_t)k * 64 + (c - 2048)];
    o[i] = f2bf(v);
  }
  *(ushort4*)&wt[(size_t)c * 1024 + k0]     = *(ushort4*)&o[0];
  *(ushort4*)&wt[(size_t)c * 1024 + k0 + 4] = *(ushort4*)&o[4];
}

// ---------------- 3. GEMM (m97 pattern) + fused V-transpose epilogue ----------------
__global__ __launch_bounds__(256) void k_gemm(const unsigned short* __restrict__ A,
                                              const unsigned short* __restrict__ Bt,
                                              unsigned short* __restrict__ C,
                                              unsigned short* __restrict__ vst) {
  __shared__ unsigned short As[128 * 32];   // linear: required by global_load_lds
  __shared__ unsigned short Bs[128 * 32];
  const int L = blockIdx.x;                 // XCD swizzle: 1088 = 8 * 136
  const int wi = (L & 7) * 136 + (L >> 3);
  const int tn = wi % 17, tm = wi / 17;
  const int rowBase = tm * 128, colBase = tn * 128;
  const int t = threadIdx.x;
  const int wave = t >> 6, lane = t & 63;
  const int wm = wave >> 1, wn = wave & 1;
  const int l15 = lane & 15, l4 = lane >> 4;
  f32x4 acc[4][4] = {};
  for (int kt = 0; kt < 1024; kt += 32) {
#pragma unroll
    for (int i = 0; i < 2; ++i) {
      int e = (t + i * 256) * 8;          // elem index in 128x32 tile
      int r = e >> 5, c = e & 31;
      gload16(&A[(size_t)(rowBase + r) * 1024 + kt + c], &As[e]);
      int rb = colBase + r; rb = rb < NC ? rb : (NC - 1);   // clamp (dup row, never stored)
      gload16(&Bt[(size_t)rb * 1024 + kt + c], &Bs[e]);
    }
    __syncthreads();
    bf16x8 af[4], bfr[4];
#pragma unroll
    for (int m = 0; m < 4; ++m) af[m] = *(const bf16x8*)&As[(wm * 64 + m * 16 + l15) * 32 + l4 * 8];
#pragma unroll
    for (int n = 0; n < 4; ++n) bfr[n] = *(const bf16x8*)&Bs[(wn * 64 + n * 16 + l15) * 32 + l4 * 8];
#pragma unroll
    for (int m = 0; m < 4; ++m)
#pragma unroll
      for (int n = 0; n < 4; ++n)
        acc[m][n] = __builtin_amdgcn_mfma_f32_16x16x32_bf16(af[m], bfr[n], acc[m][n], 0, 0, 0);
    __syncthreads();
  }
#pragma unroll
  for (int m = 0; m < 4; ++m)
#pragma unroll
    for (int n = 0; n < 4; ++n) {
      int col = colBase + wn * 64 + n * 16 + l15;
      int row0 = rowBase + wm * 64 + m * 16 + l4 * 4;
      if (col < 2048) {
#pragma unroll
        for (int i = 0; i < 4; ++i)
          C[(size_t)(row0 + i) * NC + col] = f2bf_n(acc[m][n][i]);
      } else if (col < NC) {
        // V columns: write transposed into vst[b][d][j]
        int d = col - 2048;
#pragma unroll
        for (int i = 0; i < 4; ++i) {
          int rg = row0 + i;
          vst[((size_t)(rg >> 10) * 64 + d) * 1024 + (rg & 1023)] = f2bf_n(acc[m][n][i]);
        }
      }
    }
}

// ---------------- 4. attention: r4 champion structure + T5 setprio ----------------
// 8 waves x 512 threads, QBLK=32, exp-in-pass-1, single barrier,
// attn NT-stores BEFORE PV (stores drain under PV's MFMAs).
__global__ __launch_bounds__(512, 4) void k_attn(const unsigned short* __restrict__ G,
                                                 const unsigned short* __restrict__ vst,
                                                 float* __restrict__ attn,
                                                 float* __restrict__ head) {
  __shared__ unsigned short SP[32][1032];  // unnormalized exp(scores), bf16
  __shared__ float rs[32][8];              // per-row partial sums, per wave
  const int L = blockIdx.x;                // XCD swizzle: 4096 = 8 * 512
  const int wi = (L & 7) * 512 + (L >> 3);
  const int qt = wi & 31, b = (wi >> 5) & 7, h = wi >> 8;
  const int t = threadIdx.x, wave = t >> 6, lane = t & 63;
  const int l15 = lane & 15, l4 = lane >> 4;

  const unsigned short* Gb = G + (size_t)b * 1024 * NC;

  // Q fragments: rows qt*32 + m*16 + l15, cols h*64 + ks*32 + l4*8
  bf16x8 qf[2][2];
#pragma unroll
  for (int m = 0; m < 2; ++m)
#pragma unroll
    for (int ks = 0; ks < 2; ++ks)
      qf[m][ks] = *(const bf16x8*)&Gb[(size_t)(qt * 32 + m * 16 + l15) * NC + h * 64 + ks * 32 + l4 * 8];

  // ---- QK^T (wave owns keys [wave*128, +128)): exp + partial row-sums fused ----
  const float scale = 0.125f;  // 1/sqrt(64)
  float psum[2][4] = {};
#pragma unroll
  for (int half = 0; half < 2; ++half) {
    bf16x8 kf[4][2];
#pragma unroll
    for (int kt = 0; kt < 4; ++kt) {
      int k0 = wave * 128 + (half * 4 + kt) * 16;
#pragma unroll
      for (int ks = 0; ks < 2; ++ks)
        kf[kt][ks] = *(const bf16x8*)&Gb[(size_t)(k0 + l15) * NC + 1024 + h * 64 + ks * 32 + l4 * 8];
    }
#pragma unroll
    for (int kt = 0; kt < 4; ++kt) {
      int k0 = wave * 128 + (half * 4 + kt) * 16;
      f32x4 s0 = {}, s1 = {};
      __builtin_amdgcn_s_setprio(1);
      s0 = __builtin_amdgcn_mfma_f32_16x16x32_bf16(qf[0][0], kf[kt][0], s0, 0, 0, 0);
      s0 = __builtin_amdgcn_mfma_f32_16x16x32_bf16(qf[0][1], kf[kt][1], s0, 0, 0, 0);
      s1 = __builtin_amdgcn_mfma_f32_16x16x32_bf16(qf[1][0], kf[kt][0], s1, 0, 0, 0);
      s1 = __builtin_amdgcn_mfma_f32_16x16x32_bf16(qf[1][1], kf[kt][1], s1, 0, 0, 0);
      __builtin_amdgcn_s_setprio(0);
#pragma unroll
      for (int i = 0; i < 4; ++i) {
        unsigned short u0 = f2bf_n(__expf(s0[i] * scale));
        unsigned short u1 = f2bf_n(__expf(s1[i] * scale));
        SP[l4 * 4 + i][k0 + l15]      = u0;
        SP[16 + l4 * 4 + i][k0 + l15] = u1;
        psum[0][i] += bf2f(u0);
        psum[1][i] += bf2f(u1);
      }
    }
  }
  // reduce partial sums across l15 (same rows within an l4 group)
#pragma unroll
  for (int off = 1; off < 16; off <<= 1)
#pragma unroll
    for (int m = 0; m < 2; ++m)
#pragma unroll
      for (int i = 0; i < 4; ++i)
        psum[m][i] += __shfl_xor(psum[m][i], off);
  if (l15 == 0) {
#pragma unroll
    for (int m = 0; m < 2; ++m)
#pragma unroll
      for (int i = 0; i < 4; ++i)
        rs[m * 16 + l4 * 4 + i][wave] = psum[m][i];
  }
  __syncthreads();

  // ---- per-row inverse sums ----
  const int wm = wave >> 2, wn = wave & 3;
  float winv[4], pinv[4];
#pragma unroll
  for (int rr = 0; rr < 4; ++rr) {
    int row = wave * 4 + rr;
    float4 a = *(const float4*)&rs[row][0];
    float4 c = *(const float4*)&rs[row][4];
    winv[rr] = 1.0f / (a.x + a.y + a.z + a.w + c.x + c.y + c.z + c.w);
  }
#pragma unroll
  for (int i = 0; i < 4; ++i) {
    int row = wm * 16 + l4 * 4 + i;
    float4 a = *(const float4*)&rs[row][0];
    float4 c = *(const float4*)&rs[row][4];
    pinv[i] = 1.0f / (a.x + a.y + a.z + a.w + c.x + c.y + c.z + c.w);
  }

  // ---- attn write (rows wave*4..+3): scale + nontemporal fp32 store ----
  size_t attn_base = ((size_t)(h * 8 + b) * 1024 + (size_t)qt * 32) * 1024;
#pragma unroll
  for (int rr = 0; rr < 4; ++rr) {
    int row = wave * 4 + rr;
    float inv = winv[rr];
#pragma unroll
    for (int c = 0; c < 2; ++c) {
      uint4 u = *(const uint4*)&SP[row][c * 512 + lane * 8];
      f32x4 p0 = {bf2f((unsigned short)(u.x & 0xFFFF)) * inv,
                  bf2f((unsigned short)(u.x >> 16)) * inv,
                  bf2f((unsigned short)(u.y & 0xFFFF)) * inv,
                  bf2f((unsigned short)(u.y >> 16)) * inv};
      f32x4 p1 = {bf2f((unsigned short)(u.z & 0xFFFF)) * inv,
                  bf2f((unsigned short)(u.z >> 16)) * inv,
                  bf2f((unsigned short)(u.w & 0xFFFF)) * inv,
                  bf2f((unsigned short)(u.w >> 16)) * inv};
      float* ab = &attn[attn_base + (size_t)row * 1024 + c * 512 + lane * 8];
      __builtin_nontemporal_store(p0, (f32x4*)ab);
      __builtin_nontemporal_store(p1, (f32x4*)(ab + 4));
    }
  }

  // ---- PV: wave owns 16x16 tile (wm,wn); unnormalized P, scale at end ----
  const unsigned short* vb = vst + ((size_t)b * 64 + wn * 16 + l15) * 1024;
  const unsigned short* pr = &SP[wm * 16 + l15][0];
  f32x4 o0 = {}, o1 = {};
  __builtin_amdgcn_s_setprio(1);
#pragma unroll 8
  for (int jt = 0; jt < 32; jt += 2) {
    bf16x8 pa0 = *(const bf16x8*)&pr[jt * 32 + l4 * 8];
    bf16x8 bv0 = *(const bf16x8*)&vb[jt * 32 + l4 * 8];
    o0 = __builtin_amdgcn_mfma_f32_16x16x32_bf16(pa0, bv0, o0, 0, 0, 0);
    bf16x8 pa1 = *(const bf16x8*)&pr[(jt + 1) * 32 + l4 * 8];
    bf16x8 bv1 = *(const bf16x8*)&vb[(jt + 1) * 32 + l4 * 8];
    o1 = __builtin_amdgcn_mfma_f32_16x16x32_bf16(pa1, bv1, o1, 0, 0, 0);
  }
  __builtin_amdgcn_s_setprio(0);
  float* hb = head + (((size_t)(h * 8 + b) * 1024) + qt * 32 + wm * 16) * 64 + wn * 16;
#pragma unroll
  for (int i = 0; i < 4; ++i)
    hb[(size_t)(l4 * 4 + i) * 64 + l15] = (o0[i] + o1[i]) * pinv[i];
}

// ---------------- 5. fused head-mean + out = pooled @ Wo (champion 256-block version) ----------------
__global__ __launch_bounds__(256) void k_final(const float* __restrict__ head,
                                               const float* __restrict__ Wo,
                                               float* __restrict__ out) {
  __shared__ float Ps[32][68];
  __shared__ float Ws[64][132];
  const int rt = blockIdx.x;
  const int r0 = rt * 32;
  const int t = threadIdx.x;
#pragma unroll
  for (int j = 0; j < 2; ++j) {
    int e = t + j * 256;                  // 512 float4 slots = 32 rows x 16
    int r = e >> 4, k4 = (e & 15) * 4;
    float4 acc = {0.f, 0.f, 0.f, 0.f};
#pragma unroll
    for (int hh = 0; hh < 16; ++hh) {
      float4 v = *(const float4*)&head[((size_t)hh * 8192 + r0 + r) * 64 + k4];
      acc.x += v.x; acc.y += v.y; acc.z += v.z; acc.w += v.w;
    }
    const float s = 1.0f / 16.0f;
    Ps[r][k4] = acc.x * s; Ps[r][k4 + 1] = acc.y * s;
    Ps[r][k4 + 2] = acc.z * s; Ps[r][k4 + 3] = acc.w * s;
  }
  const int ty = t >> 4, tx = t & 15;
  for (int dt = 0; dt < 8; ++dt) {
    int d0 = dt * 128;
#pragma unroll
    for (int j = 0; j < 8; ++j) {
      int e = t + j * 256;
      int k = e >> 5, c4 = (e & 31) * 4;
      *(float4*)&Ws[k][c4] = *(const float4*)&Wo[(size_t)k * 1024 + d0 + c4];
    }
    __syncthreads();
    float acc[2][8] = {};
    for (int k = 0; k < 64; ++k) {
      float a0 = Ps[ty * 2][k], a1 = Ps[ty * 2 + 1][k];
      float4 b0 = *(const float4*)&Ws[k][tx * 8];
      float4 b1 = *(const float4*)&Ws[k][tx * 8 + 4];
      acc[0][0] += a0 * b0.x; acc[0][1] += a0 * b0.y; acc[0][2] += a0 * b0.z; acc[0][3] += a0 * b0.w;
      acc[0][4] += a0 * b1.x; acc[0][5] += a0 * b1.y; acc[0][6] += a0 * b1.z; acc[0][7] += a0 * b1.w;
      acc[1][0] += a1 * b0.x; acc[1][1] += a1 * b0.y; acc[1][2] += a1 * b0.z; acc[1][3] += a1 * b0.w;
      acc[1][4] += a1 * b1.x; acc[1][5] += a1 * b1.y; acc[1][6] += a1 * b1.z; acc[1][7] += a1 * b1.w;
    }
#pragma unroll
    for (int i = 0; i < 2; ++i) {
      float4 v0 = {acc[i][0], acc[i][1], acc[i][2], acc[i][3]};
      float4 v1 = {acc[i][4], acc[i][5], acc[i][6], acc[i][7]};
      size_t o = (size_t)(r0 + ty * 2 + i) * 1024 + d0 + tx * 8;
      *(float4*)&out[o]     = v0;
      *(float4*)&out[o + 4] = v1;
    }
    __syncthreads();
  }
}

extern "C" void kernel_launch(void* const* d_in, const int* in_sizes, int n_in,
                              void* d_out, int out_size, void* d_ws, size_t ws_size,
                              hipStream_t stream) {
  const float* q  = (const float*)d_in[0];
  // d_in[1] (k), d_in[2] (v) are unused by the reference
  const float* Wq = (const float*)d_in[3];
  const float* Wk = (const float*)d_in[4];
  const float* Wv = (const float*)d_in[5];
  const float* Wo = (const float*)d_in[6];

  char* ws = (char*)d_ws;
  unsigned short* qbf   = (unsigned short*)(ws + 0);          // 16,777,216 B
  unsigned short* wcatT = (unsigned short*)(ws + 16777216);   //  4,325,376 B
  unsigned short* G     = (unsigned short*)(ws + 21102592);   // 34,603,008 B
  unsigned short* vst   = (unsigned short*)(ws + 55705600);   //  1,048,576 B
  float*          head  = (float*)(ws + 56754176);            // 33,554,432 B

  float* out  = (float*)d_out;
  float* attn = out + (size_t)8 * 1024 * 1024;

  hipLaunchKernelGGL(k_convert_q,   dim3(8192), dim3(256), 0, stream, q, qbf);
  hipLaunchKernelGGL(k_build_wcatT, dim3(1056), dim3(256), 0, stream, Wq, Wk, Wv, wcatT);
  hipLaunchKernelGGL(k_gemm,        dim3(1088), dim3(256), 0, stream, qbf, wcatT, G, vst);
  hipLaunchKernelGGL(k_attn,        dim3(4096), dim3(512), 0, stream, G, vst, attn, head);
  hipLaunchKernelGGL(k_final,       dim3(256),  dim3(256), 0, stream, head, Wo, out);
}